// Round 8
// baseline (667.157 us; speedup 1.0000x reference)
//
#include <hip/hip_runtime.h>
#include <hip/hip_bf16.h>
#include <stdint.h>

// Problem constants
#define B_N     2048
#define E_N     32
#define IN_N    2048
#define OUT_N   1024
#define TOPK    4

// GEMM tiling: BM=320 (1 m-tile/expert -> W read once), BN=64, K split in 2
#define BM      320
#define BN      64
#define BK      32
#define KHALF   1024
#define NKT_H   (KHALF / BK)        // 32 k-steps per item
#define THREADS 256                 // 4 waves, wave tile 80x64 (5x4 frags)
#define GRID_GEMM 1024              // = items (32e x 16nt x 2kh); 3 resident/CU

// LDS (uint4 slots): per-buf A 1280 + W 256 = 1536; double buffered
#define WBASE   1280
#define BUFSTRIDE 1536

// ws int layout
#define WS_COUNTS 0      // [32]
#define WS_QCUR   32     // [8]
#define WS_QLEN   40     // [8]
#define WS_QUEUE  64     // [8][512]
#define WS_LISTS  4160   // [E_N][B_N] packed (b<<2)|k
#define FEATB_OFF 278784 // bytes; bf16 feat copy (8MB)

// s_getreg: id=20 (HW_REG_XCC_ID), offset=0, size=4
#define XCC_ENC (20 | (0 << 6) | (3 << 11))

typedef float  f32x4  __attribute__((ext_vector_type(4)));
typedef __bf16 bf16x8 __attribute__((ext_vector_type(8)));

union Pack8 { bf16x8 v; uint4 u; };

__device__ __forceinline__ uint4 pack8(f32x4 lo, f32x4 hi) {
  Pack8 p;
#pragma unroll
  for (int j = 0; j < 4; ++j) { p.v[j] = (__bf16)lo[j]; p.v[j + 4] = (__bf16)hi[j]; }
  return p.u;
}
__device__ __forceinline__ bf16x8 as_frag(uint4 u) { Pack8 p; p.u = u; return p.v; }

// ---------------- kernel 0: zero counters/cursors ----------------
__global__ void k_zero(int* __restrict__ ws) {
  if (threadIdx.x < 64) ws[threadIdx.x] = 0;
}

// ---------------- kernel 0a: zero output (atomic accumulate target) ----------
__global__ void k_zout(f32x4* __restrict__ o) {
  int n = B_N * TOPK * OUT_N / 4;
  for (int i = blockIdx.x * 256 + threadIdx.x; i < n; i += 2048 * 256)
    o[i] = (f32x4){0.f, 0.f, 0.f, 0.f};
}

// ---------------- kernel 0b: feat f32 -> bf16 ----------------
__global__ void k_conv(const float* __restrict__ f, unsigned short* __restrict__ o) {
  int i = (blockIdx.x * 256 + threadIdx.x) * 8;
  f32x4 a = *(const f32x4*)(f + i);
  f32x4 b = *(const f32x4*)(f + i + 4);
  *(uint4*)(o + i) = pack8(a, b);
}

// ---------------- kernel 1: top-4-smallest + bucket ----------------
__global__ void k_topk(const float* __restrict__ act, int* __restrict__ ws) {
  int b = blockIdx.x * blockDim.x + threadIdx.x;
  if (b >= B_N) return;
  float v[E_N];
  const float* a = act + (size_t)b * E_N;
#pragma unroll
  for (int e = 0; e < E_N; ++e) v[e] = a[e];
  unsigned chosen = 0;
#pragma unroll
  for (int k = 0; k < TOPK; ++k) {
    float mv = 3.4e38f; int mi = 0;
#pragma unroll
    for (int e = 0; e < E_N; ++e) {
      bool sel = (((chosen >> e) & 1u) == 0u) && (v[e] < mv);  // strict <: stable
      mv = sel ? v[e] : mv;
      mi = sel ? e : mi;
    }
    chosen |= (1u << mi);
    int pos = atomicAdd(&ws[WS_COUNTS + mi], 1);
    ws[WS_LISTS + mi * B_N + pos] = (b << 2) | k;
  }
}

// ---------------- kernel 2: per-XCD work queues ----------------
// queue q = experts e%8==q. Per expert 32 base items (kh-major, nt-inner) so
// same-A sharers are temporally clustered on one XCD. item=(e<<10)|(mt<<5)|(kh<<4)|nt
__global__ void k_tiles(int* __restrict__ ws) {
  int e = threadIdx.x;  // one wave of 64
  int c = (e < E_N) ? ws[WS_COUNTS + e] : 0;
  int tiles = (c + BM - 1) / BM;
  if (tiles < 1) tiles = 1;
  int ov = tiles - 1;                 // overflow tiles (normally 0)
  int q = e & 7, s = (e >> 3) & 3;
  int ovs[4];
#pragma unroll
  for (int t = 0; t < 4; ++t) ovs[t] = __shfl(ov, q + 8 * t, 64);
  int pre = 0, tot = 0;
#pragma unroll
  for (int t = 0; t < 4; ++t) { if (t < s) pre += ovs[t]; tot += ovs[t]; }
  if (e < E_N) {
    for (int i = 0; i < 32; ++i)
      ws[WS_QUEUE + q * 512 + s * 32 + i] = (e << 10) | i;   // mt=0, kh=i>>4, nt=i&15
    int off = 128 + pre * 32;
    for (int mt = 1; mt < tiles; ++mt)
      for (int i = 0; i < 32; ++i)
        ws[WS_QUEUE + q * 512 + off + (mt - 1) * 32 + i] = (e << 10) | (mt << 5) | i;
    if (s == 0) ws[WS_QLEN + q] = 128 + tot * 32;
  }
}

// ---------------- kernel 3: persistent grouped GEMM, K-split-2 ----------------
// Item = 320 gathered rows x 64 cols x 1024 K-half. W read exactly once chip-wide.
// Output: atomicAdd (exactly 2 addends/element -> bit-deterministic); kh=0 adds bias.
__global__ __launch_bounds__(THREADS, 3)
void k_gemm(const unsigned short* __restrict__ featb, const float* __restrict__ Wm,
            const float* __restrict__ bias, int* __restrict__ ws,
            float* __restrict__ out) {
  __shared__ uint4 lds4[2 * BUFSTRIDE];   // 48KB
  __shared__ int gids[BM];
  __shared__ int item_s;

  int tid  = threadIdx.x;
  int lane = tid & 63;
  int wv   = tid >> 6;    // 0..3, wave rows [80*wv, 80*wv+80)

  // fragment read indices (fixed)
  int aidx[5], bidx[4];
#pragma unroll
  for (int mi = 0; mi < 5; ++mi) {
    int r = wv * 80 + mi * 16 + (lane & 15);
    aidx[mi] = r * 4 + ((lane >> 4) ^ ((r >> 1) & 3));
  }
#pragma unroll
  for (int ni = 0; ni < 4; ++ni) {
    int r = ni * 16 + (lane & 15);
    bidx[ni] = WBASE + r * 4 + ((lane >> 4) ^ ((r >> 1) & 3));
  }

  // A staging: 5 slots/thread, slot l = tid + 256*i; row=l>>2, seg=l&3 (16B)
  int arow[5], aphy[5], aseg[5];
#pragma unroll
  for (int i = 0; i < 5; ++i) {
    int l = tid + 256 * i;
    arow[i] = l >> 2;
    aseg[i] = l & 3;
    aphy[i] = arow[i] * 4 + (aseg[i] ^ ((arow[i] >> 1) & 3));
  }
  // W staging: 1 slot/thread; row=tid>>2, seg=tid&3 (8 f32 -> 1 bf16x8 slot)
  int wrow = tid >> 2, wseg = tid & 3;
  int wphy = WBASE + wrow * 4 + (wseg ^ ((wrow >> 1) & 3));

  while (true) {
    if (tid == 0) {
      int xcc = (int)(__builtin_amdgcn_s_getreg(XCC_ENC)) & 7;
      int it = -1;
      for (int t8 = 0; t8 < 8; ++t8) {
        int q = (xcc + t8) & 7;
        int idx = atomicAdd(&ws[WS_QCUR + q], 1);
        if (idx < ws[WS_QLEN + q]) { it = ws[WS_QUEUE + q * 512 + idx]; break; }
      }
      item_s = it;
    }
    __syncthreads();
    int item = item_s;
    if (item < 0) return;
    int e  = item >> 10;
    int mt = (item >> 5) & 31;
    int kh = (item >> 4) & 1;
    int nt = item & 15;
    int count = ws[WS_COUNTS + e];
    int m0 = mt * BM;
    int kbase = kh * KHALF;

    if (tid < BM) {
      int gr = m0 + tid;
      gids[tid] = (gr < count) ? ws[WS_LISTS + e * B_N + gr] : -1;
    }
    if (tid + 256 < BM) {
      int gr = m0 + tid + 256;
      gids[tid + 256] = (gr < count) ? ws[WS_LISTS + e * B_N + gr] : -1;
    }
    __syncthreads();

    const unsigned short* asrc[5];
#pragma unroll
    for (int i = 0; i < 5; ++i) {
      int g = gids[arow[i]];
      g = (g >= 0) ? (g >> 2) : 0;
      asrc[i] = featb + (size_t)g * IN_N + kbase + aseg[i] * 8;
    }
    const float* wp = Wm + ((size_t)e * OUT_N + (size_t)(nt * BN + wrow)) * IN_N
                      + kbase + wseg * 8;

    uint4 ra[5];
    f32x4 rw[2];
    f32x4 acc[5][4] = {};

#define LOADK(KT)                                                            \
    do {                                                                     \
      _Pragma("unroll")                                                      \
      for (int i = 0; i < 5; ++i) ra[i] = *(const uint4*)(asrc[i] + (KT) * BK); \
      rw[0] = *(const f32x4*)(wp + (size_t)(KT) * BK);                       \
      rw[1] = *(const f32x4*)(wp + (size_t)(KT) * BK + 4);                   \
    } while (0)

#define WRITEK(BUF)                                                          \
    do {                                                                     \
      _Pragma("unroll")                                                      \
      for (int i = 0; i < 5; ++i) lds4[(BUF) * BUFSTRIDE + aphy[i]] = ra[i]; \
      lds4[(BUF) * BUFSTRIDE + wphy] = pack8(rw[0], rw[1]);                  \
    } while (0)

    LOADK(0);
    WRITEK(0);
    __syncthreads();

    int cur = 0;
#pragma unroll 1
    for (int kt = 0; kt < NKT_H; ++kt) {
      bool pf = (kt + 1 < NKT_H);
      if (pf) LOADK(kt + 1);

      int base = cur * BUFSTRIDE;
      bf16x8 af[5], bfr[4];
#pragma unroll
      for (int mi = 0; mi < 5; ++mi) af[mi] = as_frag(lds4[base + aidx[mi]]);
#pragma unroll
      for (int ni = 0; ni < 4; ++ni) bfr[ni] = as_frag(lds4[base + bidx[ni]]);
#pragma unroll
      for (int mi = 0; mi < 5; ++mi)
#pragma unroll
        for (int ni = 0; ni < 4; ++ni)
          acc[mi][ni] = __builtin_amdgcn_mfma_f32_16x16x32_bf16(af[mi], bfr[ni], acc[mi][ni], 0, 0, 0);

      if (pf) WRITEK(cur ^ 1);
      __syncthreads();
      cur ^= 1;
    }

    // epilogue: atomic accumulate; kh==0 contributes bias
#pragma unroll
    for (int ni = 0; ni < 4; ++ni) {
      int col = nt * BN + ni * 16 + (lane & 15);
      float bs = (kh == 0) ? bias[e * OUT_N + col] : 0.f;
#pragma unroll
      for (int mi = 0; mi < 5; ++mi) {
#pragma unroll
        for (int j2 = 0; j2 < 4; ++j2) {
          int g = gids[wv * 80 + mi * 16 + (lane >> 4) * 4 + j2];
          if (g >= 0) atomicAdd(&out[(size_t)g * OUT_N + col], acc[mi][ni][j2] + bs);
        }
      }
    }
    __syncthreads();   // protect gids/item_s before next pop
  }
}

extern "C" void kernel_launch(void* const* d_in, const int* in_sizes, int n_in,
                              void* d_out, int out_size, void* d_ws, size_t ws_size,
                              hipStream_t stream) {
  const float* feat = (const float*)d_in[0];   // [B, IN]
  const float* Wm   = (const float*)d_in[1];   // [E, OUT, IN]
  const float* bias = (const float*)d_in[2];   // [E, OUT]
  const float* act  = (const float*)d_in[3];   // [B, E]
  int*   ws  = (int*)d_ws;
  unsigned short* featb = (unsigned short*)((char*)d_ws + FEATB_OFF);
  float* out = (float*)d_out;

  hipLaunchKernelGGL(k_zero,  dim3(1),                 dim3(64),      0, stream, ws);
  hipLaunchKernelGGL(k_zout,  dim3(2048),              dim3(256),     0, stream, (f32x4*)out);
  hipLaunchKernelGGL(k_conv,  dim3(B_N * IN_N / 2048), dim3(256),     0, stream, feat, featb);
  hipLaunchKernelGGL(k_topk,  dim3(B_N / 256),         dim3(256),     0, stream, act, ws);
  hipLaunchKernelGGL(k_tiles, dim3(1),                 dim3(64),      0, stream, ws);
  hipLaunchKernelGGL(k_gemm,  dim3(GRID_GEMM),         dim3(THREADS), 0, stream,
                     featb, Wm, bias, ws, out);
}

// Round 9
// 538.398 us; speedup vs baseline: 1.2392x; 1.2392x over previous
//
#include <hip/hip_runtime.h>
#include <hip/hip_bf16.h>
#include <stdint.h>

// Problem constants
#define B_N     2048
#define E_N     32
#define IN_N    2048
#define OUT_N   1024
#define TOPK    4

// GEMM tiling: small items, XCD-affine scheduling, high CU coverage
#define BM      128
#define BN      128
#define BK      32
#define NKT     (IN_N / BK)         // 64 k-steps
#define THREADS 256                 // 4 waves (2m x 2n), wave tile 64x64
#define GRID_GEMM 768               // persistent; 3 blocks/CU

// LDS (uint4 slots): per-buf A 512 + W 512 = 1024 (16KB); dbuf = 32KB
#define WBASE   512
#define BUFSTRIDE 1024

// ws int layout
#define WS_COUNTS 0      // [32]
#define WS_QCUR   32     // [8]
#define WS_QLEN   40     // [8]
#define WS_QUEUE  64     // [8][512]
#define WS_LISTS  4160   // [E_N][B_N] packed (b<<2)|k
#define FEATB_OFF 278784 // bytes; bf16 feat copy (8MB)

// s_getreg: id=20 (HW_REG_XCC_ID), offset=0, size=4
#define XCC_ENC (20 | (0 << 6) | (3 << 11))

typedef float  f32x4  __attribute__((ext_vector_type(4)));
typedef __bf16 bf16x8 __attribute__((ext_vector_type(8)));

union Pack8 { bf16x8 v; uint4 u; };

__device__ __forceinline__ uint4 pack8(f32x4 lo, f32x4 hi) {
  Pack8 p;
#pragma unroll
  for (int j = 0; j < 4; ++j) { p.v[j] = (__bf16)lo[j]; p.v[j + 4] = (__bf16)hi[j]; }
  return p.u;
}
__device__ __forceinline__ bf16x8 as_frag(uint4 u) { Pack8 p; p.u = u; return p.v; }

// ---------------- kernel 0: zero counters/cursors ----------------
__global__ void k_zero(int* __restrict__ ws) {
  if (threadIdx.x < 64) ws[threadIdx.x] = 0;
}

// ---------------- kernel 0b: feat f32 -> bf16 ----------------
__global__ void k_conv(const float* __restrict__ f, unsigned short* __restrict__ o) {
  int i = (blockIdx.x * 256 + threadIdx.x) * 8;
  f32x4 a = *(const f32x4*)(f + i);
  f32x4 b = *(const f32x4*)(f + i + 4);
  *(uint4*)(o + i) = pack8(a, b);
}

// ---------------- kernel 1: top-4-smallest + bucket ----------------
__global__ void k_topk(const float* __restrict__ act, int* __restrict__ ws) {
  int b = blockIdx.x * blockDim.x + threadIdx.x;
  if (b >= B_N) return;
  float v[E_N];
  const float* a = act + (size_t)b * E_N;
#pragma unroll
  for (int e = 0; e < E_N; ++e) v[e] = a[e];
  unsigned chosen = 0;
#pragma unroll
  for (int k = 0; k < TOPK; ++k) {
    float mv = 3.4e38f; int mi = 0;
#pragma unroll
    for (int e = 0; e < E_N; ++e) {
      bool sel = (((chosen >> e) & 1u) == 0u) && (v[e] < mv);  // strict <: stable
      mv = sel ? v[e] : mv;
      mi = sel ? e : mi;
    }
    chosen |= (1u << mi);
    int pos = atomicAdd(&ws[WS_COUNTS + mi], 1);
    ws[WS_LISTS + mi * B_N + pos] = (b << 2) | k;
  }
}

// ---------------- kernel 2: per-XCD work queues ----------------
// queue q = experts e%8==q. Per expert: nt-outer, mt-inner so the m-tiles
// sharing one W slice pop adjacently, and one expert's whole item set
// (~16 items) is co-resident on its XCD -> W/A re-reads are L2 hits.
// item = (e<<10)|(mt<<4)|nt
__global__ void k_tiles(int* __restrict__ ws) {
  int q = threadIdx.x;
  if (q >= 8) return;
  int n = 0;
  for (int s = 0; s < 4; ++s) {
    int e = q + 8 * s;
    int c = ws[WS_COUNTS + e];
    int tiles = (c + BM - 1) / BM;
    for (int nt = 0; nt < 8; ++nt)
      for (int mt = 0; mt < tiles; ++mt)
        ws[WS_QUEUE + q * 512 + (n++)] = (e << 10) | (mt << 4) | nt;
  }
  ws[WS_QLEN + q] = n;
}

// ---------------- kernel 3: persistent grouped GEMM ----------------
// Item = 128 gathered rows x 128 cols, full K. Pop from own XCD's queue
// (HW_REG_XCC_ID), steal when empty. Reg prefetch + LDS dbuf (R5 pattern).
__global__ __launch_bounds__(THREADS, 3)
void k_gemm(const unsigned short* __restrict__ featb, const float* __restrict__ Wm,
            const float* __restrict__ bias, int* __restrict__ ws,
            float* __restrict__ out) {
  __shared__ uint4 lds4[2 * BUFSTRIDE];   // 32KB
  __shared__ int gids[BM];
  __shared__ int item_s;

  int tid  = threadIdx.x;
  int lane = tid & 63;
  int wv   = tid >> 6;
  int wm   = wv >> 1;   // 0..1
  int wn   = wv & 1;    // 0..1

  // fragment read indices (fixed)
  int aidx[4], bidx[4];
#pragma unroll
  for (int mi = 0; mi < 4; ++mi) {
    int r = wm * 64 + mi * 16 + (lane & 15);
    aidx[mi] = r * 4 + ((lane >> 4) ^ ((r >> 1) & 3));
  }
#pragma unroll
  for (int ni = 0; ni < 4; ++ni) {
    int r = wn * 64 + ni * 16 + (lane & 15);
    bidx[ni] = WBASE + r * 4 + ((lane >> 4) ^ ((r >> 1) & 3));
  }

  // A staging: 2 slots/thread; slot l = tid + 256*i; row=l>>2, seg=l&3 (16B)
  int arow[2], aseg[2], aphy[2];
#pragma unroll
  for (int i = 0; i < 2; ++i) {
    int l = tid + 256 * i;
    arow[i] = l >> 2;
    aseg[i] = l & 3;
    aphy[i] = arow[i] * 4 + (aseg[i] ^ ((arow[i] >> 1) & 3));
  }
  // W staging: row = tid>>1, half = tid&1 (16 floats -> 2 bf16x8 slots)
  int wrow = tid >> 1, half = tid & 1;
  int wswz = (wrow >> 1) & 3;
  int wsl0 = WBASE + wrow * 4 + ((half * 2) ^ wswz);
  int wsl1 = WBASE + wrow * 4 + ((half * 2 + 1) ^ wswz);

  while (true) {
    // ---- pop one item with XCD affinity ----
    if (tid == 0) {
      int xcc = (int)(__builtin_amdgcn_s_getreg(XCC_ENC)) & 7;
      int it = -1;
      for (int t8 = 0; t8 < 8; ++t8) {
        int q = (xcc + t8) & 7;
        int idx = atomicAdd(&ws[WS_QCUR + q], 1);
        if (idx < ws[WS_QLEN + q]) { it = ws[WS_QUEUE + q * 512 + idx]; break; }
      }
      item_s = it;
    }
    __syncthreads();
    int item = item_s;
    if (item < 0) return;
    int e  = item >> 10;
    int mt = (item >> 4) & 63;
    int nt = item & 15;
    int count = ws[WS_COUNTS + e];
    int m0 = mt * BM;

    if (tid < BM) {
      int gr = m0 + tid;
      gids[tid] = (gr < count) ? ws[WS_LISTS + e * B_N + gr] : -1;
    }
    __syncthreads();

    const unsigned short* asrc[2];
#pragma unroll
    for (int i = 0; i < 2; ++i) {
      int g = gids[arow[i]];
      g = (g >= 0) ? (g >> 2) : 0;
      asrc[i] = featb + (size_t)g * IN_N + aseg[i] * 8;
    }
    const float* wp = Wm + ((size_t)e * OUT_N + (size_t)(nt * BN + wrow)) * IN_N + half * 16;

    uint4 ra[2];
    f32x4 rw[4];
    f32x4 acc[4][4] = {};

#define LOADK(KT)                                                            \
    do {                                                                     \
      ra[0] = *(const uint4*)(asrc[0] + (KT) * BK);                          \
      ra[1] = *(const uint4*)(asrc[1] + (KT) * BK);                          \
      _Pragma("unroll")                                                      \
      for (int i = 0; i < 4; ++i) rw[i] = *(const f32x4*)(wp + (size_t)(KT) * BK + i * 4); \
    } while (0)

#define WRITEK(BUF)                                                          \
    do {                                                                     \
      lds4[(BUF) * BUFSTRIDE + aphy[0]] = ra[0];                             \
      lds4[(BUF) * BUFSTRIDE + aphy[1]] = ra[1];                             \
      lds4[(BUF) * BUFSTRIDE + wsl0] = pack8(rw[0], rw[1]);                  \
      lds4[(BUF) * BUFSTRIDE + wsl1] = pack8(rw[2], rw[3]);                  \
    } while (0)

    LOADK(0);
    WRITEK(0);
    __syncthreads();

    int cur = 0;
#pragma unroll 1
    for (int kt = 0; kt < NKT; ++kt) {
      bool pf = (kt + 1 < NKT);
      if (pf) LOADK(kt + 1);

      int base = cur * BUFSTRIDE;
      bf16x8 af[4], bfr[4];
#pragma unroll
      for (int mi = 0; mi < 4; ++mi) af[mi] = as_frag(lds4[base + aidx[mi]]);
#pragma unroll
      for (int ni = 0; ni < 4; ++ni) bfr[ni] = as_frag(lds4[base + bidx[ni]]);
#pragma unroll
      for (int mi = 0; mi < 4; ++mi)
#pragma unroll
        for (int ni = 0; ni < 4; ++ni)
          acc[mi][ni] = __builtin_amdgcn_mfma_f32_16x16x32_bf16(af[mi], bfr[ni], acc[mi][ni], 0, 0, 0);

      if (pf) WRITEK(cur ^ 1);
      __syncthreads();
      cur ^= 1;
    }

    // ---- store: D row=(lane>>4)*4+j, col=lane&15 ----
#pragma unroll
    for (int ni = 0; ni < 4; ++ni) {
      int col = nt * BN + wn * 64 + ni * 16 + (lane & 15);
      float bs = bias[e * OUT_N + col];
#pragma unroll
      for (int mi = 0; mi < 4; ++mi) {
#pragma unroll
        for (int j2 = 0; j2 < 4; ++j2) {
          int g = gids[wm * 64 + mi * 16 + (lane >> 4) * 4 + j2];
          if (g >= 0) out[(size_t)g * OUT_N + col] = acc[mi][ni][j2] + bs;
        }
      }
    }
    __syncthreads();   // protect gids/item_s before next pop
  }
}

extern "C" void kernel_launch(void* const* d_in, const int* in_sizes, int n_in,
                              void* d_out, int out_size, void* d_ws, size_t ws_size,
                              hipStream_t stream) {
  const float* feat = (const float*)d_in[0];   // [B, IN]
  const float* Wm   = (const float*)d_in[1];   // [E, OUT, IN]
  const float* bias = (const float*)d_in[2];   // [E, OUT]
  const float* act  = (const float*)d_in[3];   // [B, E]
  int*   ws  = (int*)d_ws;
  unsigned short* featb = (unsigned short*)((char*)d_ws + FEATB_OFF);
  float* out = (float*)d_out;

  hipLaunchKernelGGL(k_zero,  dim3(1),                 dim3(64),      0, stream, ws);
  hipLaunchKernelGGL(k_conv,  dim3(B_N * IN_N / 2048), dim3(256),     0, stream, feat, featb);
  hipLaunchKernelGGL(k_topk,  dim3(B_N / 256),         dim3(256),     0, stream, act, ws);
  hipLaunchKernelGGL(k_tiles, dim3(1),                 dim3(64),      0, stream, ws);
  hipLaunchKernelGGL(k_gemm,  dim3(GRID_GEMM),         dim3(THREADS), 0, stream,
                     featb, Wm, bias, ws, out);
}

// Round 10
// 225.721 us; speedup vs baseline: 2.9557x; 2.3852x over previous
//
#include <hip/hip_runtime.h>
#include <hip/hip_bf16.h>
#include <stdint.h>

// Problem constants
#define B_N     2048
#define E_N     32
#define IN_N    2048
#define OUT_N   1024
#define TOPK    4

// GEMM tiling: BM=384 -> 1 m-tile/expert (W read once); BN=128 -> 8 nt;
// static grid, 256 active blocks (1/CU), nt spread across XCDs.
#define BM      384
#define BN      128
#define BK      32
#define NKT     (IN_N / BK)         // 64 k-steps
#define THREADS 512                 // 8 waves: 4m x 2n, wave tile 96x64
#define MAX_SLOTS 56                // sum ceil(c_e/384) <= 8192/384+32 ~= 53
#define GRID_GEMM (MAX_SLOTS * 8)   // 448 (inactive exit); active ~256

// LDS (uint4 slots): per-buf A 384x4=1536 + W 128x4=512 = 2048 (32KB); dbuf 64KB
#define WBASE   1536
#define BUFSTRIDE 2048

// ws int layout
#define WS_COUNTS 0     // [32]
#define WS_NSLOTS 32    // [1]
#define WS_DESC   64    // [MAX_SLOTS] packed (e<<6)|mt
#define WS_LISTS  256   // [E_N][B_N] packed (b<<2)|k
#define FEATB_OFF 264192 // bytes; bf16 feat copy (8MB)

typedef float  f32x4  __attribute__((ext_vector_type(4)));
typedef __bf16 bf16x8 __attribute__((ext_vector_type(8)));

union Pack8 { bf16x8 v; uint4 u; };

__device__ __forceinline__ uint4 pack8(f32x4 lo, f32x4 hi) {
  Pack8 p;
#pragma unroll
  for (int j = 0; j < 4; ++j) { p.v[j] = (__bf16)lo[j]; p.v[j + 4] = (__bf16)hi[j]; }
  return p.u;
}
__device__ __forceinline__ bf16x8 as_frag(uint4 u) { Pack8 p; p.u = u; return p.v; }

// ---------------- kernel 0: zero counters ----------------
__global__ void k_zero(int* __restrict__ ws) {
  if (threadIdx.x < 64) ws[threadIdx.x] = 0;
}

// ---------------- kernel 0b: feat f32 -> bf16 ----------------
__global__ void k_conv(const float* __restrict__ f, unsigned short* __restrict__ o) {
  int i = (blockIdx.x * 256 + threadIdx.x) * 8;
  f32x4 a = *(const f32x4*)(f + i);
  f32x4 b = *(const f32x4*)(f + i + 4);
  *(uint4*)(o + i) = pack8(a, b);
}

// ---------------- kernel 1: top-4-smallest + bucket ----------------
__global__ void k_topk(const float* __restrict__ act, int* __restrict__ ws) {
  int b = blockIdx.x * blockDim.x + threadIdx.x;
  if (b >= B_N) return;
  float v[E_N];
  const float* a = act + (size_t)b * E_N;
#pragma unroll
  for (int e = 0; e < E_N; ++e) v[e] = a[e];
  unsigned chosen = 0;
#pragma unroll
  for (int k = 0; k < TOPK; ++k) {
    float mv = 3.4e38f; int mi = 0;
#pragma unroll
    for (int e = 0; e < E_N; ++e) {
      bool sel = (((chosen >> e) & 1u) == 0u) && (v[e] < mv);  // strict <: stable
      mv = sel ? v[e] : mv;
      mi = sel ? e : mi;
    }
    chosen |= (1u << mi);
    int pos = atomicAdd(&ws[WS_COUNTS + mi], 1);
    ws[WS_LISTS + mi * B_N + pos] = (b << 2) | k;
  }
}

// ---------------- kernel 2: build tile worklist ----------------
__global__ void k_tiles(int* __restrict__ ws) {
  int e = threadIdx.x;  // one wave of 64
  int c = (e < E_N) ? ws[WS_COUNTS + e] : 0;
  int t = (e < E_N) ? ((c + BM - 1) / BM) : 0;
  if (e < E_N && t < 1) t = 1;
  int off = 0, tot = 0;
  for (int j = 0; j < E_N; ++j) {
    int tj = __shfl(t, j, 64);
    if (j < e) off += tj;
    tot += tj;
  }
  if (e < E_N) {
    for (int i = 0; i < t; ++i) ws[WS_DESC + off + i] = (e << 6) | i;
  }
  if (e == 0) ws[WS_NSLOTS] = tot;
}

// ---------------- kernel 3: grouped GEMM (bf16 MFMA), static grid ----------------
// Block = slot (expert m-tile, 384 rows) x nt (128 cols), full K.
// slot = p>>3, nt = p&7: one expert's 8 nt-blocks spread across 8 XCDs.
// Reg prefetch + LDS dbuf, 1 barrier/k-step (R3/R5-proven loop).
__global__ __launch_bounds__(THREADS, 1)
void k_gemm(const unsigned short* __restrict__ featb, const float* __restrict__ Wm,
            const float* __restrict__ bias, const int* __restrict__ ws,
            float* __restrict__ out) {
  int p = blockIdx.x;
  int slot = p >> 3;
  int nt   = p & 7;
  if (slot >= ws[WS_NSLOTS]) return;
  int desc = ws[WS_DESC + slot];
  int e = desc >> 6, mt = desc & 63;
  int count = ws[WS_COUNTS + e];
  int m0 = mt * BM;

  __shared__ uint4 lds4[2 * BUFSTRIDE];   // 64KB
  __shared__ int gids[BM];

  int tid  = threadIdx.x;
  int lane = tid & 63;
  int wv   = tid >> 6;
  int wm   = wv >> 1;   // 0..3  (96-row stripes)
  int wn   = wv & 1;    // 0..1  (64-col stripes)

  // gids (384 rows)
  if (tid < BM) {
    int gr = m0 + tid;
    gids[tid] = (gr < count) ? ws[WS_LISTS + e * B_N + gr] : -1;
  }
  __syncthreads();

  // --- A staging: 3 slots/thread; slot l = tid + 512*i; row=l>>2, seg=l&3 ---
  int aphy[3];
  const unsigned short* asrc[3];
#pragma unroll
  for (int i = 0; i < 3; ++i) {
    int l = tid + 512 * i;
    int row = l >> 2, seg = l & 3;
    aphy[i] = row * 4 + (seg ^ ((row >> 1) & 3));
    int g = gids[row];
    g = (g >= 0) ? (g >> 2) : 0;
    asrc[i] = featb + (size_t)g * IN_N + seg * 8;
  }
  // --- W staging: 1 slot/thread; row=tid>>2, seg=tid&3 (8 f32) ---
  int wrow = tid >> 2, wseg = tid & 3;
  const float* wp = Wm + ((size_t)e * OUT_N + (size_t)(nt * BN + wrow)) * IN_N + wseg * 8;
  int wphy = WBASE + wrow * 4 + (wseg ^ ((wrow >> 1) & 3));

  // --- fragment read indices (uint4 units, swizzled) ---
  int aidx[6], bidx[4];
#pragma unroll
  for (int mi = 0; mi < 6; ++mi) {
    int r = wm * 96 + mi * 16 + (lane & 15);
    aidx[mi] = r * 4 + ((lane >> 4) ^ ((r >> 1) & 3));
  }
#pragma unroll
  for (int ni = 0; ni < 4; ++ni) {
    int r = wn * 64 + ni * 16 + (lane & 15);
    bidx[ni] = WBASE + r * 4 + ((lane >> 4) ^ ((r >> 1) & 3));
  }

  uint4 ra[3];
  f32x4 rw[2];
  f32x4 acc[6][4] = {};  // 96 AGPRs

#define LOADK(KT)                                                            \
  do {                                                                       \
    ra[0] = *(const uint4*)(asrc[0] + (KT) * BK);                            \
    ra[1] = *(const uint4*)(asrc[1] + (KT) * BK);                            \
    ra[2] = *(const uint4*)(asrc[2] + (KT) * BK);                            \
    rw[0] = *(const f32x4*)(wp + (size_t)(KT) * BK);                         \
    rw[1] = *(const f32x4*)(wp + (size_t)(KT) * BK + 4);                     \
  } while (0)

#define WRITEK(BUF)                                                          \
  do {                                                                       \
    lds4[(BUF) * BUFSTRIDE + aphy[0]] = ra[0];                               \
    lds4[(BUF) * BUFSTRIDE + aphy[1]] = ra[1];                               \
    lds4[(BUF) * BUFSTRIDE + aphy[2]] = ra[2];                               \
    lds4[(BUF) * BUFSTRIDE + wphy]    = pack8(rw[0], rw[1]);                 \
  } while (0)

  LOADK(0);
  WRITEK(0);
  __syncthreads();

  int cur = 0;
#pragma unroll 1
  for (int kt = 0; kt < NKT; ++kt) {
    bool pf = (kt + 1 < NKT);
    if (pf) LOADK(kt + 1);   // issue next tile's loads first

    int base = cur * BUFSTRIDE;
    bf16x8 af[6], bfr[4];
#pragma unroll
    for (int mi = 0; mi < 6; ++mi) af[mi] = as_frag(lds4[base + aidx[mi]]);
#pragma unroll
    for (int ni = 0; ni < 4; ++ni) bfr[ni] = as_frag(lds4[base + bidx[ni]]);
#pragma unroll
    for (int mi = 0; mi < 6; ++mi)
#pragma unroll
      for (int ni = 0; ni < 4; ++ni)
        acc[mi][ni] = __builtin_amdgcn_mfma_f32_16x16x32_bf16(af[mi], bfr[ni], acc[mi][ni], 0, 0, 0);

    if (pf) WRITEK(cur ^ 1);
    __syncthreads();
    cur ^= 1;
  }

  // --- store: D row=(lane>>4)*4+j, col=lane&15 ---
#pragma unroll
  for (int ni = 0; ni < 4; ++ni) {
    int col = nt * BN + wn * 64 + ni * 16 + (lane & 15);
    float bs = bias[e * OUT_N + col];
#pragma unroll
    for (int mi = 0; mi < 6; ++mi) {
#pragma unroll
      for (int j2 = 0; j2 < 4; ++j2) {
        int g = gids[wm * 96 + mi * 16 + (lane >> 4) * 4 + j2];
        if (g >= 0) out[(size_t)g * OUT_N + col] = acc[mi][ni][j2] + bs;
      }
    }
  }
}

extern "C" void kernel_launch(void* const* d_in, const int* in_sizes, int n_in,
                              void* d_out, int out_size, void* d_ws, size_t ws_size,
                              hipStream_t stream) {
  const float* feat = (const float*)d_in[0];   // [B, IN]
  const float* Wm   = (const float*)d_in[1];   // [E, OUT, IN]
  const float* bias = (const float*)d_in[2];   // [E, OUT]
  const float* act  = (const float*)d_in[3];   // [B, E]
  int*   ws  = (int*)d_ws;
  unsigned short* featb = (unsigned short*)((char*)d_ws + FEATB_OFF);
  float* out = (float*)d_out;

  hipLaunchKernelGGL(k_zero,  dim3(1),                 dim3(64),      0, stream, ws);
  hipLaunchKernelGGL(k_conv,  dim3(B_N * IN_N / 2048), dim3(256),     0, stream, feat, featb);
  hipLaunchKernelGGL(k_topk,  dim3(B_N / 256),         dim3(256),     0, stream, act, ws);
  hipLaunchKernelGGL(k_tiles, dim3(1),                 dim3(64),      0, stream, ws);
  hipLaunchKernelGGL(k_gemm,  dim3(GRID_GEMM),         dim3(THREADS), 0, stream,
                     featb, Wm, bias, ws, out);
}